// Round 2
// 737.809 us; speedup vs baseline: 1.0008x; 1.0008x over previous
//
#include <hip/hip_runtime.h>
#include <hip/hip_bf16.h>

#define LDIM 4096
#define FDIM 64
#define BM 64
#define BK 256
#define NIT (LDIM / BK)   // 16
#define SAP 264           // LDS row stride in bf16 elems (256 + 8 pad)

typedef __attribute__((ext_vector_type(8))) __bf16 bf16x8;
typedef __attribute__((ext_vector_type(4))) float f32x4;

__device__ __forceinline__ unsigned short f2bf(float f) {
    unsigned int u = __float_as_uint(f);
    u += 0x7fffu + ((u >> 16) & 1u);       // round-to-nearest-even
    return (unsigned short)(u >> 16);
}

// Kernel 1: hiddenT[b][o][l] = sum_f text[b][l][f] * weight[f][o], stored bf16 (bits)
// Transposed layout so kernel 2's B-fragment reads are contiguous in k.
__global__ __launch_bounds__(256) void hidden_kernel(
    const float* __restrict__ text, const float* __restrict__ weight,
    unsigned short* __restrict__ hT)
{
    const int b  = blockIdx.x & 7;
    const int lc = blockIdx.x >> 3;        // 0..63
    const int l0 = lc * 64;
    __shared__ float sw[64 * 64];          // weight [f][o]
    __shared__ float st[64 * 65];          // text tile [l][f], +1 pad
    const int t = threadIdx.x;
    #pragma unroll
    for (int i = 0; i < 16; ++i) sw[t + i * 256] = weight[t + i * 256];
    const float* tp = text + ((size_t)b * LDIM + l0) * FDIM;
    #pragma unroll
    for (int i = 0; i < 16; ++i) {
        int idx = t + i * 256;
        st[(idx >> 6) * 65 + (idx & 63)] = tp[idx];
    }
    __syncthreads();
    const int l  = t & 63;                 // lane = l -> coalesced bf16 row writes
    const int o0 = (t >> 6) * 16;
    float acc[16];
    #pragma unroll
    for (int i = 0; i < 16; ++i) acc[i] = 0.f;
    for (int f = 0; f < 64; ++f) {
        float tv = st[l * 65 + f];
        #pragma unroll
        for (int i = 0; i < 16; ++i) acc[i] += tv * sw[f * 64 + o0 + i];
    }
    unsigned short* hp = hT + ((size_t)b * FDIM + o0) * LDIM + l0 + l;
    #pragma unroll
    for (int i = 0; i < 16; ++i) hp[(size_t)i * LDIM] = f2bf(acc[i]);
}

// Kernel 2: out[b] = adj[b] @ hidden[b] + bias.  M=4096 N=64 K=4096 per batch.
// BM=64, full N=64, BK=256: each adj row contributes 1 KB contiguous per iter,
// and each A-load instruction is one full contiguous 1 KB row per wave.
// 4 waves, each: 16 M-rows x 64 N-cols (1x4 16x16x32 frags), 8 k-steps/iter.
__global__ __launch_bounds__(256, 2) void gemm_kernel(
    const float* __restrict__ adj, const unsigned short* __restrict__ hT,
    const float* __restrict__ bias, float* __restrict__ out)
{
    const int b  = blockIdx.x & 7;         // batch -> XCD affinity (hidden[b] L2-resident)
    const int mb = blockIdx.x >> 3;        // 0..63
    const int m0 = mb * BM;
    const int tid  = threadIdx.x;
    const int w    = tid >> 6;
    const int lane = tid & 63;

    __shared__ __align__(16) unsigned short sA[BM * SAP];   // A[m][k] bf16, 33.8 KB
    __shared__ __align__(16) unsigned short sB[64 * SAP];   // B stored [n][k] bf16, 33.8 KB

    const float*          abase = adj + ((size_t)b * LDIM + m0) * LDIM;
    const unsigned short* hbase = hT + (size_t)b * FDIM * LDIM;

    // A tile: 64 rows x 256 f32 = 4096 float4. Thread t, instr i -> idx = i*256+t:
    //   row = idx>>6, col4 = idx&63.  Instr i = wave reads ONE contiguous 1 KB row.
    // B tile: 64 rows x 256 bf16 = 2048 uint4. idx = i*256+t: row = idx>>5, col16 = idx&31.
    float4 aReg[16]; uint4 bReg[8];

    // prologue: tile 0
    #pragma unroll
    for (int i = 0; i < 16; ++i) {
        int idx = i * 256 + tid;
        aReg[i] = *(const float4*)(abase + (size_t)(idx >> 6) * LDIM + (idx & 63) * 4);
    }
    #pragma unroll
    for (int i = 0; i < 8; ++i) {
        int idx = i * 256 + tid;
        bReg[i] = *(const uint4*)(hbase + (size_t)(idx >> 5) * LDIM + (idx & 31) * 8);
    }

    f32x4 acc[4];
    #pragma unroll
    for (int nf = 0; nf < 4; ++nf) acc[nf] = (f32x4){0.f, 0.f, 0.f, 0.f};

    const int fm = lane & 15;
    const int fq = lane >> 4;

    for (int it = 0; it < NIT; ++it) {
        __syncthreads();                   // prev iter's fragment reads done
        // convert + store A (vmcnt waits happen here: this is the BW-bound phase;
        // the other resident block computes meanwhile)
        #pragma unroll
        for (int i = 0; i < 16; ++i) {
            int idx = i * 256 + tid;
            union { unsigned short us[4]; uint2 v; } pk;
            pk.us[0] = f2bf(aReg[i].x); pk.us[1] = f2bf(aReg[i].y);
            pk.us[2] = f2bf(aReg[i].z); pk.us[3] = f2bf(aReg[i].w);
            *(uint2*)&sA[(idx >> 6) * SAP + (idx & 63) * 4] = pk.v;
        }
        #pragma unroll
        for (int i = 0; i < 8; ++i) {
            int idx = i * 256 + tid;
            *(uint4*)&sB[(idx >> 5) * SAP + (idx & 31) * 8] = bReg[i];
        }
        __syncthreads();

        // issue next K-tile loads immediately (in flight across the MFMA phase
        // and the other block's phases; consumed at next iter's LDS-write)
        if (it + 1 < NIT) {
            const int k0 = (it + 1) * BK;
            #pragma unroll
            for (int i = 0; i < 16; ++i) {
                int idx = i * 256 + tid;
                aReg[i] = *(const float4*)(abase + (size_t)(idx >> 6) * LDIM + k0 + (idx & 63) * 4);
            }
            #pragma unroll
            for (int i = 0; i < 8; ++i) {
                int idx = i * 256 + tid;
                bReg[i] = *(const uint4*)(hbase + (size_t)(idx >> 5) * LDIM + k0 + (idx & 31) * 8);
            }
        }

        #pragma unroll
        for (int kf = 0; kf < 8; ++kf) {
            bf16x8 af = *(const bf16x8*)&sA[(w * 16 + fm) * SAP + kf * 32 + fq * 8];
            #pragma unroll
            for (int nf = 0; nf < 4; ++nf) {
                bf16x8 bfr = *(const bf16x8*)&sB[(nf * 16 + fm) * SAP + kf * 32 + fq * 8];
                acc[nf] = __builtin_amdgcn_mfma_f32_16x16x32_bf16(af, bfr, acc[nf], 0, 0, 0);
            }
        }
    }

    // epilogue: C/D layout col = lane&15, row = (lane>>4)*4 + reg
    float* obase = out + ((size_t)b * LDIM + m0 + w * 16 + fq * 4) * FDIM + fm;
    #pragma unroll
    for (int nf = 0; nf < 4; ++nf) {
        float bv = bias[nf * 16 + fm];
        #pragma unroll
        for (int r = 0; r < 4; ++r)
            obase[(size_t)r * FDIM + nf * 16] = acc[nf][r] + bv;
    }
}

extern "C" void kernel_launch(void* const* d_in, const int* in_sizes, int n_in,
                              void* d_out, int out_size, void* d_ws, size_t ws_size,
                              hipStream_t stream) {
    const float* text   = (const float*)d_in[0];
    const float* adj    = (const float*)d_in[1];
    const float* weight = (const float*)d_in[2];
    const float* bias   = (const float*)d_in[3];
    float* out = (float*)d_out;
    unsigned short* hT = (unsigned short*)d_ws;   // 8*64*4096*2 = 4 MB

    hidden_kernel<<<512, 256, 0, stream>>>(text, weight, hT);
    gemm_kernel<<<512, 256, 0, stream>>>(adj, hT, bias, out);
}